// Round 6
// baseline (336.847 us; speedup 1.0000x reference)
//
#include <hip/hip_runtime.h>
#include <math.h>

// Problem dims (fixed by setup_inputs)
constexpr int Bc = 64;
constexpr int Tc = 1000;
constexpr int Vc = 512;
constexpr int Uc = 256;
constexpr int CH = 50;        // t-rows per LDS chunk
constexpr int NCH = Tc / CH;  // 20 chunks
constexpr int PW = 7;         // producer waves (waves 1..7); wave 0 = consumer
constexpr int RW = 8;         // max rows per producer wave per chunk (ceil(50/7))

#define NEG_INF_F (-100000.0f)
#define LOG2E_F 1.44269504088896340736f
#define LN2_F 0.69314718055994530942f
#define DEAD_F (-1.0e9f)

// raw v_exp_f32 (2^x) / v_log_f32 (log2 x)
__device__ __forceinline__ float fexp2(float x) {
#if __has_builtin(__builtin_amdgcn_exp2f)
    return __builtin_amdgcn_exp2f(x);
#else
    return __expf(x * LN2_F);
#endif
}
__device__ __forceinline__ float flog2(float x) {
#if __has_builtin(__builtin_amdgcn_logf)
    return __builtin_amdgcn_logf(x);
#else
    return __logf(x) * LOG2E_F;
#endif
}

// log2-domain logadd: log2(2^x + 2^y)
__device__ __forceinline__ float l2add(float x, float y) {
    float m = fmaxf(x, y);
    float p = fexp2(-fabsf(x - y)); // v_exp_f32 with -|.| source modifiers
    return m + flog2(1.0f + p);     // v_log_f32
}

// One HMM step in shifted log2 domain:
//   r_i(t) = log2add(r_i(t-1), r_{i-1}(t-1)) + E2_i(t)
// (transition constants pre-folded into E2 by the producer; shift d=-1 on
// non-last states, 0 on the last state makes the step uniform).
// Lane holds states i = 4*lane + c; only c=0 crosses lanes, and that link is
// on the dependency chain only once per 4 steps (slack >> shfl latency).
__device__ __forceinline__ void hmm_step(float rr[4], const float4 ev, float pen) {
    float nb0 = __shfl_up(rr[3], 1, 64) + pen; // lane0: own value - 1e9 ~= -inf
    float e[4] = {ev.x, ev.y, ev.z, ev.w};
    float nb[4] = {nb0, rr[0], rr[1], rr[2]};
#pragma unroll
    for (int c = 0; c < 4; ++c) {
        float x = rr[c], y = nb[c];
        float m = fmaxf(x, y);
        float p = fexp2(-fabsf(x - y));
        rr[c] = m + flog2(1.0f + p) + e[c];
    }
}

__global__ __launch_bounds__(512, 1) void fused_hmm_kernel(
    const float* __restrict__ lp, const float* __restrict__ lens,
    const int* __restrict__ phns, const float* __restrict__ phn_lens,
    float* __restrict__ out) {
    __shared__ float ebuf[2][CH][Uc];  // 100 KB: gathered emissions (E2 form)
    __shared__ float stage[PW][2][Vc]; // 28 KB: per-producer-wave row staging
    const int b = blockIdx.x;
    const int tid = threadIdx.x;
    const int wave = tid >> 6;
    const int lane = tid & 63;
    const int Tv = (int)rintf(lens[b] * (float)Tc);
    const int Uv = (int)rintf(phn_lens[b] * (float)Uc);
    const float* lpb = lp + (size_t)b * Tc * Vc;

    // ---------------- producer state ----------------
    int col[4];
    float off[4];
    bool pv[4];
    float* st0 = nullptr;
    float* st1 = nullptr;
    // ---------------- consumer state ----------------
    float rr[4];
    const float pen = (lane == 0) ? DEAD_F : 0.0f;

    if (wave > 0) {
        const int widx = wave - 1;
        int4 cc = *(const int4*)(phns + (size_t)b * Uc + 4 * lane);
        int c4[4] = {cc.x, cc.y, cc.z, cc.w};
#pragma unroll
        for (int c = 0; c < 4; ++c) {
            int v = c4[c];
            v = v < 0 ? 0 : (v > Vc - 1 ? Vc - 1 : v);
            col[c] = v;
            int i = 4 * lane + c;
            pv[c] = (i < Uv);
            off[c] = (i == Uv - 1) ? 0.0f : -1.0f; // -1 = transition const (log2 units)
        }
        st0 = &stage[widx][0][0];
        st1 = &stage[widx][1][0];
    }

    // producer: gather chunk k into ebuf[k&1].
    // ALL of this wave's global loads for the chunk are issued up-front into a
    // fully-unrolled register queue (16 dwordx4 in flight per wave -> MLP
    // covers HBM latency once per chunk, overlapped with the consumer's scan
    // of the previous chunk). Rows then drain through the per-wave LDS stage
    // (coalesced b128 writes, scattered b32 gathers, coalesced b128 ebuf
    // write); fine-grained vmcnt waits are compiler-inserted per row.
    auto fill = [&](int k) {
        float* dst = &ebuf[k & 1][0][0];
        const int tb = k * CH;
        const int r0 = wave - 1;
        float4 q[RW][2];
#pragma unroll
        for (int j = 0; j < RW; ++j) {
            int r = r0 + j * PW;
            int t = tb + r;
            if (r < CH && t < Tv) {
                const float4* rp = (const float4*)(lpb + (size_t)t * Vc);
                q[j][0] = rp[lane];
                q[j][1] = rp[64 + lane];
            }
        }
#pragma unroll
        for (int j = 0; j < RW; ++j) {
            int r = r0 + j * PW;
            if (r < CH) {
                const int t = tb + r;
                const bool tv = (t < Tv);
                float* st = (j & 1) ? st1 : st0;
                if (tv) {
                    ((float4*)st)[lane] = q[j][0];      // coalesced b128 LDS writes
                    ((float4*)st)[64 + lane] = q[j][1];
                }
                float ev[4];
#pragma unroll
                for (int c = 0; c < 4; ++c) {
                    float e = st[col[c]]; // random-bank ds_read_b32 (cheap)
                    ev[c] = (pv[c] && tv) ? fmaf(e, LOG2E_F, off[c])
                                          : (NEG_INF_F * LOG2E_F + off[c]);
                }
                *(float4*)(dst + r * Uc + 4 * lane) =
                    make_float4(ev[0], ev[1], ev[2], ev[3]);
            }
        }
    };

    // consumer: scan chunk k from LDS with a 4-deep register pipeline
    auto consume = [&](int k) {
        const float4* base = (const float4*)&ebuf[k & 1][0][0] + lane; // row stride 64
        int r = 0;
        if (k == 0) {
            float4 e0 = base[0];
            float ea[4] = {e0.x, e0.y, e0.z, e0.w};
#pragma unroll
            for (int c = 0; c < 4; ++c)
                rr[c] = ((4 * lane + c == 0) ? 0.0f : DEAD_F) + ea[c]; // pi + E2(0)
            r = 1;
        }
        float4 q0, q1, q2, q3;
        if (r + 0 < CH) q0 = base[(r + 0) * 64];
        if (r + 1 < CH) q1 = base[(r + 1) * 64];
        if (r + 2 < CH) q2 = base[(r + 2) * 64];
        if (r + 3 < CH) q3 = base[(r + 3) * 64];
        while (r + 4 <= CH) {
            float4 e0 = q0, e1 = q1, e2 = q2, e3 = q3;
            if (r + 4 < CH) q0 = base[(r + 4) * 64];
            if (r + 5 < CH) q1 = base[(r + 5) * 64];
            if (r + 6 < CH) q2 = base[(r + 6) * 64];
            if (r + 7 < CH) q3 = base[(r + 7) * 64];
            hmm_step(rr, e0, pen);
            hmm_step(rr, e1, pen);
            hmm_step(rr, e2, pen);
            hmm_step(rr, e3, pen);
            r += 4;
        }
        if (r + 0 < CH) hmm_step(rr, q0, pen);
        if (r + 1 < CH) hmm_step(rr, q1, pen);
        if (r + 2 < CH) hmm_step(rr, q2, pen);
    };

    // ---- pipeline: barriers OUTSIDE the role branch (uniform count) ----
    if (wave > 0) fill(0);
    __syncthreads();
    for (int k = 0; k < NCH; ++k) {
        if (wave > 0) {
            if (k + 1 < NCH) fill(k + 1);
        } else {
            consume(k);
        }
        __syncthreads();
    }

    if (wave == 0) {
        // undo the shift (+1 on non-last states), then logsumexp over states
        float a[4];
#pragma unroll
        for (int c = 0; c < 4; ++c)
            a[c] = rr[c] + ((4 * lane + c == Uv - 1) ? 0.0f : 1.0f);
        float r2 = l2add(l2add(a[0], a[1]), l2add(a[2], a[3]));
#pragma unroll
        for (int o = 32; o >= 1; o >>= 1) {
            float t = __shfl_xor(r2, o, 64);
            r2 = l2add(r2, t);
        }
        if (lane == 0) out[b] = r2 * LN2_F; // back to nats
    }
}

extern "C" void kernel_launch(void* const* d_in, const int* in_sizes, int n_in,
                              void* d_out, int out_size, void* d_ws, size_t ws_size,
                              hipStream_t stream) {
    const float* lp = (const float*)d_in[0];
    const float* lens = (const float*)d_in[1];
    const int* phns = (const int*)d_in[2];
    const float* phn_lens = (const float*)d_in[3];
    float* out = (float*)d_out;
    (void)d_ws; (void)ws_size; (void)in_sizes; (void)n_in; (void)out_size;

    fused_hmm_kernel<<<Bc, 512, 0, stream>>>(lp, lens, phns, phn_lens, out);
}

// Round 7
// 269.318 us; speedup vs baseline: 1.2507x; 1.2507x over previous
//
#include <hip/hip_runtime.h>
#include <math.h>

// Problem dims (fixed by setup_inputs)
constexpr int Bc = 64;
constexpr int Tc = 1000;
constexpr int Vc = 512;
constexpr int Uc = 256;
constexpr int CH = 50;        // t-rows per LDS chunk
constexpr int NCH = Tc / CH;  // 20 chunks
constexpr int PW = 7;         // producer waves (waves 1..7); wave 0 = consumer
constexpr int SLOTS = 4;      // stage slots per producer wave (DMA batch size)

#define NEG_INF_F (-100000.0f)
#define LOG2E_F 1.44269504088896340736f
#define LN2_F 0.69314718055994530942f
#define DEAD_F (-1.0e9f)

// raw v_exp_f32 (2^x) / v_log_f32 (log2 x)
__device__ __forceinline__ float fexp2(float x) {
#if __has_builtin(__builtin_amdgcn_exp2f)
    return __builtin_amdgcn_exp2f(x);
#else
    return __expf(x * LN2_F);
#endif
}
__device__ __forceinline__ float flog2(float x) {
#if __has_builtin(__builtin_amdgcn_logf)
    return __builtin_amdgcn_logf(x);
#else
    return __logf(x) * LOG2E_F;
#endif
}

// log2-domain logadd: log2(2^x + 2^y)
__device__ __forceinline__ float l2add(float x, float y) {
    float m = fmaxf(x, y);
    float p = fexp2(-fabsf(x - y)); // v_exp_f32 with -|.| source modifiers
    return m + flog2(1.0f + p);     // v_log_f32
}

// One HMM step in shifted log2 domain:
//   r_i(t) = log2add(r_i(t-1), r_{i-1}(t-1)) + E2_i(t)
// (transition constants pre-folded into E2; shift d=-1 on non-last states).
// Lane holds states i = 4*lane + c; only c=0 crosses lanes, and that link is
// on the dependency chain only once per 4 steps (slack >> shfl latency).
__device__ __forceinline__ void hmm_step(float rr[4], const float4 ev, float pen) {
    float nb0 = __shfl_up(rr[3], 1, 64) + pen; // lane0: own value - 1e9 ~= -inf
    float e[4] = {ev.x, ev.y, ev.z, ev.w};
    float nb[4] = {nb0, rr[0], rr[1], rr[2]};
#pragma unroll
    for (int c = 0; c < 4; ++c) {
        float x = rr[c], y = nb[c];
        float m = fmaxf(x, y);
        float p = fexp2(-fabsf(x - y));
        rr[c] = m + flog2(1.0f + p) + e[c];
    }
}

// async global->LDS DMA of 16 B/lane (1 KB per wave-instruction)
__device__ __forceinline__ void dma16(const float* gsrc, float* lds, int lane) {
    typedef const __attribute__((address_space(1))) unsigned int* gp_t;
    typedef __attribute__((address_space(3))) unsigned int* lp_t;
    __builtin_amdgcn_global_load_lds((gp_t)(const void*)(gsrc + 4 * lane),
                                     (lp_t)(void*)lds, 16, 0, 0);
}

__global__ __launch_bounds__(512, 1) void fused_hmm_kernel(
    const float* __restrict__ lp, const float* __restrict__ lens,
    const int* __restrict__ phns, const float* __restrict__ phn_lens,
    float* __restrict__ out) {
    __shared__ float ebuf[2][CH][Uc];      // 100 KB: gathered emissions (E2 form)
    __shared__ float stage[PW][SLOTS][Vc]; // 56 KB: per-wave DMA row staging
    const int b = blockIdx.x;
    const int tid = threadIdx.x;
    const int wave = tid >> 6;
    const int lane = tid & 63;
    const int Tv = (int)rintf(lens[b] * (float)Tc);
    const int Uv = (int)rintf(phn_lens[b] * (float)Uc);
    const float* lpb = lp + (size_t)b * Tc * Vc;

    // ---------------- producer state ----------------
    int col[4];
    float off[4];
    bool pv[4];
    // ---------------- consumer state ----------------
    float rr[4];
    const float pen = (lane == 0) ? DEAD_F : 0.0f;

    if (wave > 0) {
        int4 cc = *(const int4*)(phns + (size_t)b * Uc + 4 * lane);
        int c4[4] = {cc.x, cc.y, cc.z, cc.w};
#pragma unroll
        for (int c = 0; c < 4; ++c) {
            int v = c4[c];
            v = v < 0 ? 0 : (v > Vc - 1 ? Vc - 1 : v);
            col[c] = v;
            int i = 4 * lane + c;
            pv[c] = (i < Uv);
            off[c] = (i == Uv - 1) ? 0.0f : -1.0f; // -1 = transition const (log2 units)
        }
    }

    // producer: gather chunk k into ebuf[k&1].
    // Rows round-robin across 7 producer waves (r = wave-1 + j*7). Two DMA
    // batches of up to 4 rows: issue 8 global_load_lds (zero VGPR, deep HW
    // queue), one vmcnt(0) wait, then drain through LDS (scattered b32
    // gathers, transform, coalesced b128 ebuf write). Latency paid ~2x per
    // chunk instead of per-row; overlapped with the consumer's scan of the
    // previous chunk. All branch conditions are wave-uniform (DMA exec-safe).
    auto fill = [&](int k) {
        float* dst = &ebuf[k & 1][0][0];
        const int tb = k * CH;
        const int r0 = wave - 1;
        float* stw = &stage[wave - 1][0][0];
#pragma unroll
        for (int half = 0; half < 2; ++half) {
#pragma unroll
            for (int jj = 0; jj < SLOTS; ++jj) {
                int r = r0 + (half * SLOTS + jj) * PW;
                if (r < CH) {
                    const float* gsrc = lpb + (size_t)(tb + r) * Vc;
                    float* st = stw + jj * Vc;
                    dma16(gsrc, st, lane);             // floats [0..255]
                    dma16(gsrc + 256, st + 256, lane); // floats [256..511]
                }
            }
            __builtin_amdgcn_s_waitcnt(0x0f70); // vmcnt(0), ignore exp/lgkm
#pragma unroll
            for (int jj = 0; jj < SLOTS; ++jj) {
                int r = r0 + (half * SLOTS + jj) * PW;
                if (r < CH) {
                    const bool tv = (tb + r) < Tv;
                    const float* st = stw + jj * Vc;
                    float ev[4];
#pragma unroll
                    for (int c = 0; c < 4; ++c) {
                        float e = st[col[c]]; // random-bank ds_read_b32 (cheap)
                        ev[c] = (pv[c] && tv) ? fmaf(e, LOG2E_F, off[c])
                                              : (NEG_INF_F * LOG2E_F + off[c]);
                    }
                    *(float4*)(dst + r * Uc + 4 * lane) =
                        make_float4(ev[0], ev[1], ev[2], ev[3]);
                }
            }
        }
    };

    // consumer: scan chunk k from LDS with a 4-deep register pipeline
    auto consume = [&](int k) {
        const float4* base = (const float4*)&ebuf[k & 1][0][0] + lane; // row stride 64
        int r = 0;
        if (k == 0) {
            float4 e0 = base[0];
            float ea[4] = {e0.x, e0.y, e0.z, e0.w};
#pragma unroll
            for (int c = 0; c < 4; ++c)
                rr[c] = ((4 * lane + c == 0) ? 0.0f : DEAD_F) + ea[c]; // pi + E2(0)
            r = 1;
        }
        float4 q0, q1, q2, q3;
        if (r + 0 < CH) q0 = base[(r + 0) * 64];
        if (r + 1 < CH) q1 = base[(r + 1) * 64];
        if (r + 2 < CH) q2 = base[(r + 2) * 64];
        if (r + 3 < CH) q3 = base[(r + 3) * 64];
        while (r + 4 <= CH) {
            float4 e0 = q0, e1 = q1, e2 = q2, e3 = q3;
            if (r + 4 < CH) q0 = base[(r + 4) * 64];
            if (r + 5 < CH) q1 = base[(r + 5) * 64];
            if (r + 6 < CH) q2 = base[(r + 6) * 64];
            if (r + 7 < CH) q3 = base[(r + 7) * 64];
            hmm_step(rr, e0, pen);
            hmm_step(rr, e1, pen);
            hmm_step(rr, e2, pen);
            hmm_step(rr, e3, pen);
            r += 4;
        }
        if (r + 0 < CH) hmm_step(rr, q0, pen);
        if (r + 1 < CH) hmm_step(rr, q1, pen);
        if (r + 2 < CH) hmm_step(rr, q2, pen);
    };

    // ---- pipeline: barriers OUTSIDE the role branch (uniform count) ----
    if (wave > 0) fill(0);
    __syncthreads();
    for (int k = 0; k < NCH; ++k) {
        if (wave > 0) {
            if (k + 1 < NCH) fill(k + 1);
        } else {
            consume(k);
        }
        __syncthreads();
    }

    if (wave == 0) {
        // undo the shift (+1 on non-last states), then logsumexp over states
        float a[4];
#pragma unroll
        for (int c = 0; c < 4; ++c)
            a[c] = rr[c] + ((4 * lane + c == Uv - 1) ? 0.0f : 1.0f);
        float r2 = l2add(l2add(a[0], a[1]), l2add(a[2], a[3]));
#pragma unroll
        for (int o = 32; o >= 1; o >>= 1) {
            float t = __shfl_xor(r2, o, 64);
            r2 = l2add(r2, t);
        }
        if (lane == 0) out[b] = r2 * LN2_F; // back to nats
    }
}

extern "C" void kernel_launch(void* const* d_in, const int* in_sizes, int n_in,
                              void* d_out, int out_size, void* d_ws, size_t ws_size,
                              hipStream_t stream) {
    const float* lp = (const float*)d_in[0];
    const float* lens = (const float*)d_in[1];
    const int* phns = (const int*)d_in[2];
    const float* phn_lens = (const float*)d_in[3];
    float* out = (float*)d_out;
    (void)d_ws; (void)ws_size; (void)in_sizes; (void)n_in; (void)out_size;

    fused_hmm_kernel<<<Bc, 512, 0, stream>>>(lp, lens, phns, phn_lens, out);
}